// Round 11
// baseline (195.076 us; speedup 1.0000x reference)
//
#include <hip/hip_runtime.h>
#include <hip/hip_bf16.h>
#include <stdint.h>

// Problem constants
#define NROWS 4096
#define NCLS  97
#define EMB   768
#define KTOT  49152                 // EMB * 64
#define OUT_ELEMS (NROWS * NCLS)    // 397312
#define WT_BYTES ((size_t)KTOT * 128 * 2)    // 12,582,912 (Wt, f16, 128 padded classes)

typedef __attribute__((ext_vector_type(4)))  float floatx4;
typedef _Float16 f16x2 __attribute__((ext_vector_type(2)));
typedef _Float16 f16x8 __attribute__((ext_vector_type(8)));

typedef __attribute__((address_space(3))) uint32_t lds_u32;
typedef __attribute__((address_space(1))) uint32_t glb_u32;

// Async global->LDS, 16B/lane: LDS dest = wave-uniform base + lane*16,
// global src = per-lane address (guide m97/m104). Zero VGPR staging.
__device__ __forceinline__ void gl_lds16(const void* g, void* l) {
  __builtin_amdgcn_global_load_lds((const glb_u32*)(uintptr_t)g,
                                   (lds_u32*)(uintptr_t)l, 16, 0, 0);
}

// Pack 8 f32 -> 8 f16 as a uint4.
__device__ __forceinline__ uint4 cvt8h(float4 a, float4 b) {
  f16x8 v;
  v[0] = (_Float16)a.x; v[1] = (_Float16)a.y; v[2] = (_Float16)a.z; v[3] = (_Float16)a.w;
  v[4] = (_Float16)b.x; v[5] = (_Float16)b.y; v[6] = (_Float16)b.z; v[7] = (_Float16)b.w;
  return __builtin_bit_cast(uint4, v);
}

// Prep R19 (R20 = resubmit; R19 died on infra "container failed twice", the
// same signature R4 hit where a byte-identical resubmit passed; source
// re-audited: barriers uniform, layout verified, no dynamic reg indexing).
// Wt in FRAGMENT-LINEAR order so a straight linear LDS copy of a 16KB
// window IS the conflict-free MFMA fragment layout.
// 16B chunk index t: c16=t&15, eo=(t>>4)&3, ct=(t>>6)&3, chalf=(t>>8)&1,
// kh=(t>>9)&1, win=t>>10. Chunk t <-> W[c=chalf*64+ct*16+c16]
// [k = win*64+kh*32+eo*8 .. +7] (f16, zero-padded c>=97).
// Reader: fragment (kh,chalf,ct) = contiguous 1KB at
// (kh*8+chalf*4+ct)*1024; lane l's 16B = fragbase + l*16 (since the MFMA
// B-frag wants c16=l&15, eo=l>>4 and chunk-in-frag = eo*16+c16 = l).
__global__ void prep(const float* __restrict__ W, uint4* __restrict__ wt)
{
  const int nwt = (int)(WT_BYTES / 16);    // 786,432
  int t = blockIdx.x * blockDim.x + threadIdx.x;
  if (t >= nwt) return;
  int c16   = t & 15;
  int eo    = (t >> 4) & 3;
  int ct    = (t >> 6) & 3;
  int chalf = (t >> 8) & 1;
  int kh    = (t >> 9) & 1;
  int win   = t >> 10;
  int c = chalf * 64 + ct * 16 + c16;
  int k = win * 64 + kh * 32 + eo * 8;
  uint4 v = uint4{0u, 0u, 0u, 0u};
  if (c < NCLS) {
    const float4* p = (const float4*)(W + (size_t)c * KTOT + k);
    v = cvt8h(p[0], p[1]);
  }
  wt[t] = v;
}

// Fused on-the-fly-A GEMM, R20 (= R19): m97 structure (global_load_lds +
// LDS dbuf + single barrier/window), fragment-linear Wt.
// Ledger: R10-R18 MfmaUtil pinned 24-30% across 5 register-level schedules.
// R18 (asm counted-vmcnt ping-pong) proved register prefetch dies by regalloc
// spill (VGPR=112 < needed ~143 => scratch traffic, both pipes idle 57%).
// R17 (LDS) died on an 8-way ds_read bank conflict (2.75M) + double drain.
// This fixes both: Wt relayout makes every fragment read a CONTIGUOUS 1KB
// ds_read_b128 (conflict-free baseline, m134) and staging a zero-VGPR
// global_load_lds linear copy; one __syncthreads per window (its vmcnt(0)
// drains loads issued a full window earlier - m97's known ~20% cost, which
// still measured 37% MfmaUtil / 874 TF on this exact pattern).
// Occupancy: regs ~134 total -> launch_bounds(256,3); KS=24 -> grid (24,32)
// = 768 blocks = 3 blocks/CU = 3 waves/SIMD; LDS 32KB x 3 = 96KB/CU.
// klen=2048 -> ONE kblk per block (b2 loaded once, no mid-loop reloads);
// 24%8==0 keeps XCD co-location (linear id %8 = x%8).
// MFMA 16x16x32 verified triple:
//   A: lane l holds A[m=l&15][k=(l>>4)*8+j]; B: W[c=l&15][k=(l>>4)*8+j]
//   D: lane l, reg r: col(c)=l&15, row(n)=(l>>4)*4+r
__global__ __launch_bounds__(256, 3)
void bilinear_main(const float* __restrict__ b1f,
                   const float* __restrict__ b2f,
                   const char* __restrict__ Wt,
                   const float* __restrict__ biasg,
                   float* __restrict__ P,
                   float* __restrict__ outd,
                   int klen)
{
  const int tid  = threadIdx.x;
  const int w    = tid >> 6;
  const int l    = tid & 63;
  const int l15  = l & 15;
  const int quad = l >> 4;
  const int mhalf = w & 1;
  const int chalf = w >> 1;
  const bool cfull = (chalf == 0);   // chalf=1 waves skip ct==3 (zero pad)
  const int bm = blockIdx.y;
  const int k0 = blockIdx.x * klen;

  __shared__ char sW[2][16384];       // double-buffered window

  int nrow[4];
#pragma unroll
  for (int rt = 0; rt < 4; ++rt) nrow[rt] = bm * 128 + mhalf * 64 + rt * 16 + l15;

  const char* wtwin = Wt + (size_t)(k0 >> 6) * 16384;  // this block's windows

  floatx4 acc[4][4];
#pragma unroll
  for (int rt = 0; rt < 4; ++rt)
#pragma unroll
    for (int ct = 0; ct < 4; ++ct)
      acc[rt][ct] = floatx4{0.f, 0.f, 0.f, 0.f};

  // b2 in f16 pairs: one kblk per block (klen=2048), loaded once.
  const int kb = k0 >> 12;
  const int i0 = (k0 >> 6) & 63;      // 0 or 32
  f16x2 b2h[4][2][4];
#pragma unroll
  for (int rt = 0; rt < 4; ++rt)
#pragma unroll
    for (int kh = 0; kh < 2; ++kh) {
      const float* p = b2f + (size_t)nrow[rt] * EMB + kb * 64 + kh * 32 + quad * 8;
      float4 v0 = ((const float4*)p)[0];
      float4 v1 = ((const float4*)p)[1];
      b2h[rt][kh][0][0] = (_Float16)v0.x; b2h[rt][kh][0][1] = (_Float16)v0.y;
      b2h[rt][kh][1][0] = (_Float16)v0.z; b2h[rt][kh][1][1] = (_Float16)v0.w;
      b2h[rt][kh][2][0] = (_Float16)v1.x; b2h[rt][kh][2][1] = (_Float16)v1.y;
      b2h[rt][kh][3][0] = (_Float16)v1.z; b2h[rt][kh][3][1] = (_Float16)v1.w;
    }

  float4 b1cur[4], b1nxt[4];
#pragma unroll
  for (int rt = 0; rt < 4; ++rt)
    b1cur[rt] = *(const float4*)(b1f + (size_t)nrow[rt] * EMB + kb * 64 + i0);

  const int nwin = klen >> 6;         // 32
  const int ngrp = nwin >> 2;         // 8

  // Prologue: stage window 0 into buf 0 (wave w owns chunks [w*4KB, +4KB)).
  {
    const char* src = wtwin + w * 4096 + l * 16;
    char* dst = &sW[0][w * 4096];
#pragma unroll
    for (int i = 0; i < 4; ++i)
      gl_lds16(src + i * 1024, dst + i * 1024);
  }
  __syncthreads();

  for (int gp = 0; gp < ngrp; ++gp) {
    {
      // prefetch next group's b1 float4 (hidden under 4 windows of compute)
      const int hg = (gp + 1 < ngrp) ? gp + 1 : gp;
#pragma unroll
      for (int rt = 0; rt < 4; ++rt)
        b1nxt[rt] = *(const float4*)(b1f + (size_t)nrow[rt] * EMB +
                                     kb * 64 + i0 + hg * 4);
    }

#pragma unroll
    for (int s = 0; s < 4; ++s) {
      const int iw = gp * 4 + s;
      const int cb = iw & 1;          // read buffer
      const int nb = cb ^ 1;          // stage buffer

      // (1) stage window iw+1 (async, zero VGPR; drained at the barrier)
      if (iw + 1 < nwin) {
        const char* src = wtwin + (size_t)(iw + 1) * 16384 + w * 4096 + l * 16;
        char* dst = &sW[nb][w * 4096];
#pragma unroll
        for (int i = 0; i < 4; ++i)
          gl_lds16(src + i * 1024, dst + i * 1024);
      }

      // (2) fragment reads: contiguous 1KB ds_read_b128 per (kh,ct)
      uint4 wf[2][4];
#pragma unroll
      for (int kh = 0; kh < 2; ++kh)
#pragma unroll
        for (int ct = 0; ct < 4; ++ct)
          if (ct < 3 || cfull)
            wf[kh][ct] = ((const uint4*)(&sW[cb][0] +
                            (kh * 8 + chalf * 4 + ct) * 1024))[l];

      // A-build (native f16 pk_mul) + MFMA
      f16x2 sv[4];
#pragma unroll
      for (int rt = 0; rt < 4; ++rt) {
        _Float16 h = (_Float16)((&b1cur[rt].x)[s]);
        sv[rt][0] = h; sv[rt][1] = h;
      }
#pragma unroll
      for (int kh = 0; kh < 2; ++kh)
#pragma unroll
        for (int rt = 0; rt < 4; ++rt) {
          f16x2 p0 = sv[rt] * b2h[rt][kh][0];
          f16x2 p1 = sv[rt] * b2h[rt][kh][1];
          f16x2 p2 = sv[rt] * b2h[rt][kh][2];
          f16x2 p3 = sv[rt] * b2h[rt][kh][3];
          uint4 au;
          au.x = __builtin_bit_cast(uint32_t, p0);
          au.y = __builtin_bit_cast(uint32_t, p1);
          au.z = __builtin_bit_cast(uint32_t, p2);
          au.w = __builtin_bit_cast(uint32_t, p3);
          f16x8 af = __builtin_bit_cast(f16x8, au);
#pragma unroll
          for (int ct = 0; ct < 4; ++ct)
            if (ct < 3 || cfull)
              acc[rt][ct] = __builtin_amdgcn_mfma_f32_16x16x32_f16(
                  af, __builtin_bit_cast(f16x8, wf[kh][ct]),
                  acc[rt][ct], 0, 0, 0);
        }

      // (3) one barrier per window: drains the stage (issued ~1 window ago)
      // and flips buffers. m97 pattern.
      __syncthreads();
    }
#pragma unroll
    for (int rt = 0; rt < 4; ++rt) b1cur[rt] = b1nxt[rt];
  }

  // Epilogue. D: col(c)=l15, row(n)=quad*4+r within each 16x16 tile.
  if (P) {
    float* Pb = P + (size_t)blockIdx.x * OUT_ELEMS;   // slice = blockIdx.x
#pragma unroll
    for (int rt = 0; rt < 4; ++rt)
#pragma unroll
      for (int ct = 0; ct < 4; ++ct) {
        const int c = chalf * 64 + ct * 16 + l15;
        if (c < NCLS) {
#pragma unroll
          for (int r = 0; r < 4; ++r) {
            const int row = bm * 128 + mhalf * 64 + rt * 16 + quad * 4 + r;
            Pb[(size_t)row * NCLS + c] = acc[rt][ct][r];
          }
        }
      }
  } else {
#pragma unroll
    for (int rt = 0; rt < 4; ++rt)
#pragma unroll
      for (int ct = 0; ct < 4; ++ct) {
        const int c = chalf * 64 + ct * 16 + l15;
        if (c < NCLS) {
          const float bv = biasg[c];
#pragma unroll
          for (int r = 0; r < 4; ++r) {
            const int row = bm * 128 + mhalf * 64 + rt * 16 + quad * 4 + r;
            outd[(size_t)row * NCLS + c] = acc[rt][ct][r] + bv;
          }
        }
      }
  }
}

// Sum KS partial slices + f32 bias -> f32 output. float4-vectorized,
// KS templated so the accumulation loop fully unrolls.
template<int KSC>
__global__ void reduce_bias_t(const float* __restrict__ P,
                              const float* __restrict__ biasg,
                              float* __restrict__ out)
{
  int i = blockIdx.x * blockDim.x + threadIdx.x;
  const int n4 = OUT_ELEMS / 4;           // 99328
  if (i >= n4) return;
  int c0 = (i * 4) % NCLS;
  int c1 = c0 + 1 == NCLS ? 0 : c0 + 1;
  int c2 = c1 + 1 == NCLS ? 0 : c1 + 1;
  int c3 = c2 + 1 == NCLS ? 0 : c2 + 1;
  float4 s;
  s.x = biasg[c0]; s.y = biasg[c1]; s.z = biasg[c2]; s.w = biasg[c3];
  const float4* P4 = (const float4*)P;
#pragma unroll
  for (int t = 0; t < KSC; ++t) {
    float4 v = P4[(size_t)t * n4 + i];
    s.x += v.x; s.y += v.y; s.z += v.z; s.w += v.w;
  }
  ((float4*)out)[i] = s;
}

static void launch_reduce(int KS, const float* P, const float* bb, float* out,
                          hipStream_t stream) {
  const int nb = (OUT_ELEMS / 4 + 255) / 256;
  switch (KS) {
    case 24: reduce_bias_t<24><<<nb, 256, 0, stream>>>(P, bb, out); break;
    case 16: reduce_bias_t<16><<<nb, 256, 0, stream>>>(P, bb, out); break;
    case 12: reduce_bias_t<12><<<nb, 256, 0, stream>>>(P, bb, out); break;
    case 8:  reduce_bias_t<8><<<nb, 256, 0, stream>>>(P, bb, out);  break;
    case 6:  reduce_bias_t<6><<<nb, 256, 0, stream>>>(P, bb, out);  break;
    case 4:  reduce_bias_t<4><<<nb, 256, 0, stream>>>(P, bb, out);  break;
    case 3:  reduce_bias_t<3><<<nb, 256, 0, stream>>>(P, bb, out);  break;
    case 2:  reduce_bias_t<2><<<nb, 256, 0, stream>>>(P, bb, out);  break;
    default: reduce_bias_t<1><<<nb, 256, 0, stream>>>(P, bb, out);  break;
  }
}

extern "C" void kernel_launch(void* const* d_in, const int* in_sizes, int n_in,
                              void* d_out, int out_size, void* d_ws, size_t ws_size,
                              hipStream_t stream) {
  const float* b1f = (const float*)d_in[0];   // [4096,768] f32
  const float* b2f = (const float*)d_in[1];   // [4096,768] f32
  const float* Wf  = (const float*)d_in[2];   // [97, 49152] f32
  const float* bbf = (const float*)d_in[3];   // [97] f32
  float* out = (float*)d_out;

  const size_t slice = (size_t)OUT_ELEMS * 4;     // 1,589,248
  // klen = KTOT/KS must be a multiple of 512 -> KS divides 96.
  // KS=24 -> klen=2048 (one kblk/block), grid 768 = 3 blocks/CU (96KB LDS).
  static const int cands[] = {24, 16, 12, 8, 6, 4, 3, 2, 1};
  const int NC = 9;

  // Workspace plan: [Wt | P].
  int KS = 0;
  for (int i = 0; i < NC; ++i)
    if (WT_BYTES + (size_t)cands[i] * slice <= ws_size) { KS = cands[i]; break; }

  uint4* Wt = (uint4*)d_ws;
  const int nwt = (int)(WT_BYTES / 16);

  prep<<<(nwt + 255) / 256, 256, 0, stream>>>(Wf, Wt);

  if (KS > 0) {
    float* P = (float*)((char*)d_ws + WT_BYTES);
    bilinear_main<<<dim3(KS, 32), 256, 0, stream>>>(
        b1f, b2f, (const char*)Wt, bbf, P, nullptr, KTOT / KS);
    launch_reduce(KS, P, bbf, out, stream);
  } else {
    // Minimal-workspace fallback: single slice, direct f32 output.
    bilinear_main<<<dim3(1, 32), 256, 0, stream>>>(
        b1f, b2f, (const char*)Wt, bbf, nullptr, out, KTOT);
  }
}

// Round 12
// 146.387 us; speedup vs baseline: 1.3326x; 1.3326x over previous
//
#include <hip/hip_runtime.h>
#include <hip/hip_bf16.h>
#include <stdint.h>

// Problem constants
#define NROWS 4096
#define NCLS  97
#define EMB   768
#define KTOT  49152                 // EMB * 64
#define OUT_ELEMS (NROWS * NCLS)    // 397312
#define WT_BYTES ((size_t)KTOT * 128 * 2)    // 12,582,912 (Wt, f16, 128 padded classes)

typedef __attribute__((ext_vector_type(4)))  float floatx4;
typedef _Float16 f16x2 __attribute__((ext_vector_type(2)));
typedef _Float16 f16x8 __attribute__((ext_vector_type(8)));

typedef __attribute__((address_space(3))) uint32_t lds_u32;
typedef __attribute__((address_space(1))) uint32_t glb_u32;

// Async global->LDS, 16B/lane: LDS dest = wave-uniform base + lane*16,
// global src = per-lane address (guide m97/m104). Zero VGPR staging.
__device__ __forceinline__ void gl_lds16(const void* g, void* l) {
  __builtin_amdgcn_global_load_lds((const glb_u32*)(uintptr_t)g,
                                   (lds_u32*)(uintptr_t)l, 16, 0, 0);
}

// Pack 8 f32 -> 8 f16 as a uint4.
__device__ __forceinline__ uint4 cvt8h(float4 a, float4 b) {
  f16x8 v;
  v[0] = (_Float16)a.x; v[1] = (_Float16)a.y; v[2] = (_Float16)a.z; v[3] = (_Float16)a.w;
  v[4] = (_Float16)b.x; v[5] = (_Float16)b.y; v[6] = (_Float16)b.z; v[7] = (_Float16)b.w;
  return __builtin_bit_cast(uint4, v);
}

// Prep: Wt in FRAGMENT-LINEAR order so a straight linear LDS copy of a 16KB
// window IS the conflict-free MFMA fragment layout (R19 verified:
// SQ_LDS_BANK_CONFLICT = 0).
// 16B chunk index t: c16=t&15, eo=(t>>4)&3, ct=(t>>6)&3, chalf=(t>>8)&1,
// kh=(t>>9)&1, win=t>>10. Chunk t <-> W[c=chalf*64+ct*16+c16]
// [k = win*64+kh*32+eo*8 .. +7] (f16, zero-padded c>=97).
// Reader: fragment (kh,chalf,ct) = contiguous 1KB at (kh*8+chalf*4+ct)*1024;
// lane l's 16B = fragbase + l*16 (MFMA B-frag wants c16=l&15, eo=l>>4, and
// chunk-in-frag = eo*16+c16 = l).
__global__ void prep(const float* __restrict__ W, uint4* __restrict__ wt)
{
  const int nwt = (int)(WT_BYTES / 16);    // 786,432
  int t = blockIdx.x * blockDim.x + threadIdx.x;
  if (t >= nwt) return;
  int c16   = t & 15;
  int eo    = (t >> 4) & 3;
  int ct    = (t >> 6) & 3;
  int chalf = (t >> 8) & 1;
  int kh    = (t >> 9) & 1;
  int win   = t >> 10;
  int c = chalf * 64 + ct * 16 + c16;
  int k = win * 64 + kh * 32 + eo * 8;
  uint4 v = uint4{0u, 0u, 0u, 0u};
  if (c < NCLS) {
    const float4* p = (const float4*)(W + (size_t)c * KTOT + k);
    v = cvt8h(p[0], p[1]);
  }
  wt[t] = v;
}

// Fused on-the-fly-A GEMM, R21: R19 structure with the register squeeze
// REMOVED. R19/R20 post-mortem: bank-conflict 0 (fragment-linear layout
// verified) but FETCH/WRITE exploded to 148/154 MB, SYMMETRIC excess
// (+122/+116 MB) = scratch spill round-trips. VGPR=84 at launch_bounds
// (256,3): unified-RF budget ~160 - acc(64 AGPR) = ~96 arch, but working
// set needs ~190 total -> ~30 regs spilled, spill traffic at 2.6 TB/s
// buried MFMA at 17%. Fix: launch_bounds(256,2) -> 256-reg budget, zero
// spill; KS=16 -> grid (16,32) = 2 blocks/CU (matches 2 waves/SIMD,
// 16%8==0 keeps XCD co-location). klen=3072 spans <=2 kblks -> per-group
// cur_kb check (fires <=1x per block) + per-group b1 prefetch.
// Schedule (m97): stage(win+1, zero-VGPR global_load_lds) -> ds_read
// fragments (contiguous 1KB, conflict-free) + f16 A-build + 28 MFMA ->
// one __syncthreads (drains stage issued ~550 cyc earlier - mostly hidden).
// MFMA 16x16x32 verified triple:
//   A: lane l holds A[m=l&15][k=(l>>4)*8+j]; B: W[c=l&15][k=(l>>4)*8+j]
//   D: lane l, reg r: col(c)=l&15, row(n)=(l>>4)*4+r
__global__ __launch_bounds__(256, 2)
void bilinear_main(const float* __restrict__ b1f,
                   const float* __restrict__ b2f,
                   const char* __restrict__ Wt,
                   const float* __restrict__ biasg,
                   float* __restrict__ P,
                   float* __restrict__ outd,
                   int klen)
{
  const int tid  = threadIdx.x;
  const int w    = tid >> 6;
  const int l    = tid & 63;
  const int l15  = l & 15;
  const int quad = l >> 4;
  const int mhalf = w & 1;
  const int chalf = w >> 1;
  const bool cfull = (chalf == 0);   // chalf=1 waves skip ct==3 (zero pad)
  const int bm = blockIdx.y;
  const int k0 = blockIdx.x * klen;

  __shared__ char sW[2][16384];       // double-buffered window

  int nrow[4];
#pragma unroll
  for (int rt = 0; rt < 4; ++rt) nrow[rt] = bm * 128 + mhalf * 64 + rt * 16 + l15;

  const char* wtwin = Wt + (size_t)(k0 >> 6) * 16384;  // this block's windows

  floatx4 acc[4][4];
#pragma unroll
  for (int rt = 0; rt < 4; ++rt)
#pragma unroll
    for (int ct = 0; ct < 4; ++ct)
      acc[rt][ct] = floatx4{0.f, 0.f, 0.f, 0.f};

  // f16-pair cache of b2[nrow[rt], kb*64 + kh*32 + quad*8 + 2j,2j+1];
  // reloaded when the block's k-range crosses a kblk boundary (<=1x).
  f16x2 b2h[4][2][4];

#define LOADB2(kbv) do {                                                      \
    _Pragma("unroll")                                                         \
    for (int rt_ = 0; rt_ < 4; ++rt_)                                         \
      _Pragma("unroll")                                                       \
      for (int kh_ = 0; kh_ < 2; ++kh_) {                                     \
        const float* p_ = b2f + (size_t)nrow[rt_] * EMB + (kbv) * 64 +        \
                          kh_ * 32 + quad * 8;                                \
        float4 v0_ = ((const float4*)p_)[0];                                  \
        float4 v1_ = ((const float4*)p_)[1];                                  \
        b2h[rt_][kh_][0][0] = (_Float16)v0_.x; b2h[rt_][kh_][0][1] = (_Float16)v0_.y; \
        b2h[rt_][kh_][1][0] = (_Float16)v0_.z; b2h[rt_][kh_][1][1] = (_Float16)v0_.w; \
        b2h[rt_][kh_][2][0] = (_Float16)v1_.x; b2h[rt_][kh_][2][1] = (_Float16)v1_.y; \
        b2h[rt_][kh_][3][0] = (_Float16)v1_.z; b2h[rt_][kh_][3][1] = (_Float16)v1_.w; \
      }                                                                       \
  } while (0)

  const int nwin = klen >> 6;         // 48 at KS=16
  const int ngrp = nwin >> 2;         // 12

  // Prologue: b2/b1 for group 0; stage window 0 into buf 0
  // (wave w owns chunks [w*4KB, +4KB)).
  int cur_kb = k0 >> 12;
  LOADB2(cur_kb);
  float4 b1cur[4], b1nxt[4];
#pragma unroll
  for (int rt = 0; rt < 4; ++rt)
    b1cur[rt] = *(const float4*)(b1f + (size_t)nrow[rt] * EMB +
                                 cur_kb * 64 + ((k0 >> 6) & 63));
  {
    const char* src = wtwin + w * 4096 + l * 16;
    char* dst = &sW[0][w * 4096];
#pragma unroll
    for (int i = 0; i < 4; ++i)
      gl_lds16(src + i * 1024, dst + i * 1024);
  }
  __syncthreads();

  for (int gp = 0; gp < ngrp; ++gp) {
    const int kap_g = k0 + gp * 256;
    const int kb = kap_g >> 12;
    if (kb != cur_kb) { cur_kb = kb; LOADB2(kb); }   // uniform, <=1x/block
    {
      // prefetch next group's b1 float4 (hidden under 4 windows of compute)
      const int hg = (gp + 1 < ngrp) ? gp + 1 : gp;
      const int kap_h = k0 + hg * 256;
#pragma unroll
      for (int rt = 0; rt < 4; ++rt)
        b1nxt[rt] = *(const float4*)(b1f + (size_t)nrow[rt] * EMB +
                                     (kap_h >> 12) * 64 + ((kap_h >> 6) & 63));
    }

#pragma unroll
    for (int s = 0; s < 4; ++s) {
      const int iw = gp * 4 + s;
      const int cb = s & 1;           // read buffer (gp*4 even)
      const int nb = cb ^ 1;          // stage buffer

      // (1) stage window iw+1 (async, zero VGPR; drained at the barrier)
      if (iw + 1 < nwin) {
        const char* src = wtwin + (size_t)(iw + 1) * 16384 + w * 4096 + l * 16;
        char* dst = &sW[nb][w * 4096];
#pragma unroll
        for (int i = 0; i < 4; ++i)
          gl_lds16(src + i * 1024, dst + i * 1024);
      }

      // (2) fragment reads: contiguous 1KB ds_read_b128 per (kh,ct)
      uint4 wf[2][4];
#pragma unroll
      for (int kh = 0; kh < 2; ++kh)
#pragma unroll
        for (int ct = 0; ct < 4; ++ct)
          if (ct < 3 || cfull)
            wf[kh][ct] = ((const uint4*)(&sW[cb][0] +
                            (kh * 8 + chalf * 4 + ct) * 1024))[l];

      // A-build (native f16 pk_mul) + MFMA
      f16x2 sv[4];
#pragma unroll
      for (int rt = 0; rt < 4; ++rt) {
        _Float16 h = (_Float16)((&b1cur[rt].x)[s]);
        sv[rt][0] = h; sv[rt][1] = h;
      }
#pragma unroll
      for (int kh = 0; kh < 2; ++kh)
#pragma unroll
        for (int rt = 0; rt < 4; ++rt) {
          f16x2 p0 = sv[rt] * b2h[rt][kh][0];
          f16x2 p1 = sv[rt] * b2h[rt][kh][1];
          f16x2 p2 = sv[rt] * b2h[rt][kh][2];
          f16x2 p3 = sv[rt] * b2h[rt][kh][3];
          uint4 au;
          au.x = __builtin_bit_cast(uint32_t, p0);
          au.y = __builtin_bit_cast(uint32_t, p1);
          au.z = __builtin_bit_cast(uint32_t, p2);
          au.w = __builtin_bit_cast(uint32_t, p3);
          f16x8 af = __builtin_bit_cast(f16x8, au);
#pragma unroll
          for (int ct = 0; ct < 4; ++ct)
            if (ct < 3 || cfull)
              acc[rt][ct] = __builtin_amdgcn_mfma_f32_16x16x32_f16(
                  af, __builtin_bit_cast(f16x8, wf[kh][ct]),
                  acc[rt][ct], 0, 0, 0);
        }

      // (3) one barrier per window: drains the stage (issued ~550 cyc ago)
      // and flips buffers. m97 pattern.
      __syncthreads();
    }
#pragma unroll
    for (int rt = 0; rt < 4; ++rt) b1cur[rt] = b1nxt[rt];
  }
#undef LOADB2

  // Epilogue. D: col(c)=l15, row(n)=quad*4+r within each 16x16 tile.
  if (P) {
    float* Pb = P + (size_t)blockIdx.x * OUT_ELEMS;   // slice = blockIdx.x
#pragma unroll
    for (int rt = 0; rt < 4; ++rt)
#pragma unroll
      for (int ct = 0; ct < 4; ++ct) {
        const int c = chalf * 64 + ct * 16 + l15;
        if (c < NCLS) {
#pragma unroll
          for (int r = 0; r < 4; ++r) {
            const int row = bm * 128 + mhalf * 64 + rt * 16 + quad * 4 + r;
            Pb[(size_t)row * NCLS + c] = acc[rt][ct][r];
          }
        }
      }
  } else {
#pragma unroll
    for (int rt = 0; rt < 4; ++rt)
#pragma unroll
      for (int ct = 0; ct < 4; ++ct) {
        const int c = chalf * 64 + ct * 16 + l15;
        if (c < NCLS) {
          const float bv = biasg[c];
#pragma unroll
          for (int r = 0; r < 4; ++r) {
            const int row = bm * 128 + mhalf * 64 + rt * 16 + quad * 4 + r;
            outd[(size_t)row * NCLS + c] = acc[rt][ct][r] + bv;
          }
        }
      }
  }
}

// Sum KS partial slices + f32 bias -> f32 output. float4-vectorized,
// KS templated so the accumulation loop fully unrolls.
template<int KSC>
__global__ void reduce_bias_t(const float* __restrict__ P,
                              const float* __restrict__ biasg,
                              float* __restrict__ out)
{
  int i = blockIdx.x * blockDim.x + threadIdx.x;
  const int n4 = OUT_ELEMS / 4;           // 99328
  if (i >= n4) return;
  int c0 = (i * 4) % NCLS;
  int c1 = c0 + 1 == NCLS ? 0 : c0 + 1;
  int c2 = c1 + 1 == NCLS ? 0 : c1 + 1;
  int c3 = c2 + 1 == NCLS ? 0 : c2 + 1;
  float4 s;
  s.x = biasg[c0]; s.y = biasg[c1]; s.z = biasg[c2]; s.w = biasg[c3];
  const float4* P4 = (const float4*)P;
#pragma unroll
  for (int t = 0; t < KSC; ++t) {
    float4 v = P4[(size_t)t * n4 + i];
    s.x += v.x; s.y += v.y; s.z += v.z; s.w += v.w;
  }
  ((float4*)out)[i] = s;
}

static void launch_reduce(int KS, const float* P, const float* bb, float* out,
                          hipStream_t stream) {
  const int nb = (OUT_ELEMS / 4 + 255) / 256;
  switch (KS) {
    case 16: reduce_bias_t<16><<<nb, 256, 0, stream>>>(P, bb, out); break;
    case 12: reduce_bias_t<12><<<nb, 256, 0, stream>>>(P, bb, out); break;
    case 8:  reduce_bias_t<8><<<nb, 256, 0, stream>>>(P, bb, out);  break;
    case 6:  reduce_bias_t<6><<<nb, 256, 0, stream>>>(P, bb, out);  break;
    case 4:  reduce_bias_t<4><<<nb, 256, 0, stream>>>(P, bb, out);  break;
    case 3:  reduce_bias_t<3><<<nb, 256, 0, stream>>>(P, bb, out);  break;
    case 2:  reduce_bias_t<2><<<nb, 256, 0, stream>>>(P, bb, out);  break;
    default: reduce_bias_t<1><<<nb, 256, 0, stream>>>(P, bb, out);  break;
  }
}

extern "C" void kernel_launch(void* const* d_in, const int* in_sizes, int n_in,
                              void* d_out, int out_size, void* d_ws, size_t ws_size,
                              hipStream_t stream) {
  const float* b1f = (const float*)d_in[0];   // [4096,768] f32
  const float* b2f = (const float*)d_in[1];   // [4096,768] f32
  const float* Wf  = (const float*)d_in[2];   // [97, 49152] f32
  const float* bbf = (const float*)d_in[3];   // [97] f32
  float* out = (float*)d_out;

  const size_t slice = (size_t)OUT_ELEMS * 4;     // 1,589,248
  // klen = KTOT/KS must be a multiple of 512 -> KS divides 96.
  // KS=16 -> klen=3072, grid (16,32) = 512 blocks = 2 blocks/CU.
  static const int cands[] = {16, 12, 8, 6, 4, 3, 2, 1};
  const int NC = 8;

  // Workspace plan: [Wt | P].
  int KS = 0;
  for (int i = 0; i < NC; ++i)
    if (WT_BYTES + (size_t)cands[i] * slice <= ws_size) { KS = cands[i]; break; }

  uint4* Wt = (uint4*)d_ws;
  const int nwt = (int)(WT_BYTES / 16);

  prep<<<(nwt + 255) / 256, 256, 0, stream>>>(Wf, Wt);

  if (KS > 0) {
    float* P = (float*)((char*)d_ws + WT_BYTES);
    bilinear_main<<<dim3(KS, 32), 256, 0, stream>>>(
        b1f, b2f, (const char*)Wt, bbf, P, nullptr, KTOT / KS);
    launch_reduce(KS, P, bbf, out, stream);
  } else {
    // Minimal-workspace fallback: single slice, direct f32 output.
    bilinear_main<<<dim3(1, 32), 256, 0, stream>>>(
        b1f, b2f, (const char*)Wt, bbf, nullptr, out, KTOT);
  }
}